// Round 18
// baseline (45.908 us; speedup 1.0000x reference)
//
#include <hip/hip_runtime.h>
#include <math.h>

#define B 2048
#define D 64
#define G 512           // z-grid points for the F_d(z) table
#define NCH 32          // j-chunks for the table build
#define NC2 64          // j-chunks for the MFMA/LSE role (32 j each)
#define NBLK 2048       // (G/8) tgroups x 32 chunks

#define ZLO (-5.5f)
#define DZ  (11.0f / 511.0f)
#define INVDZ (511.0f / 11.0f)

typedef float v2f  __attribute__((ext_vector_type(2)));
typedef short bf16x8 __attribute__((ext_vector_type(8)));
typedef float f32x4  __attribute__((ext_vector_type(4)));

static __device__ __forceinline__ float exp2fast(float x) { return __builtin_amdgcn_exp2f(x); }
static __device__ __forceinline__ float log2fast(float x) { return __builtin_amdgcn_logf(x); }
static __device__ __forceinline__ unsigned short f2bf(float x) {
    unsigned u = __float_as_uint(x);
    u += 0x7fff + ((u >> 16) & 1);          // RNE; inputs are finite
    return (unsigned short)(u >> 16);
}

// ---------------------------------------------------------------------------
// Kernel 1: per-(j,d) constants (log2 units):  lp2 = h*z^2 + g*z + q
//   h = -0.5*log2e*exp(-lv), g = -2*mu*h, q = mu^2*h + c
// packhg[j*D+d] = { bf16(h)<<16 | bf16(g), fp32 q }  (8B)
// Zx/Wt = bf16 MFMA operands; QQ[j]=sum_d q; kl partials -> klp; out zeroed.
// ---------------------------------------------------------------------------
__global__ __launch_bounds__(256) void k_pre(
    const float* __restrict__ kl, const float* __restrict__ zm,
    const float* __restrict__ zlv, const float* __restrict__ zs,
    uint2* __restrict__ packhg, unsigned short* __restrict__ Zx,
    unsigned short* __restrict__ Wt, float* __restrict__ QQ,
    float* __restrict__ klp, float* __restrict__ out)
{
    const float LOG2E   = 1.4426950408889634f;
    const float LOG_2PI = 1.8378770664093453f;
    __shared__ float red[4];
    int wv = threadIdx.x >> 6, d = threadIdx.x & 63;
    int j = blockIdx.x * 4 + wv;
    int idx = j * D + d;
    float lv = zlv[idx];
    float mu = zm[idx];
    float zz = zs[idx];
    float is = exp2fast(-LOG2E * lv);            // e^{-lv}
    float h  = -0.5f * LOG2E * is;
    float cv = -0.5f * LOG2E * (lv + LOG_2PI);
    float g  = -2.0f * mu * h;
    float q  = fmaf(mu * mu, h, cv);
    packhg[idx] = make_uint2(((unsigned)f2bf(h) << 16) | f2bf(g),
                             __float_as_uint(q));
    Wt[j * 128 + d]      = f2bf(h);
    Wt[j * 128 + 64 + d] = f2bf(g);
    Zx[j * 128 + d]      = f2bf(zz * zz);
    Zx[j * 128 + 64 + d] = f2bf(zz);

    float qs = q, ks = kl[idx];
#pragma unroll
    for (int off = 32; off; off >>= 1) {
        qs += __shfl_xor(qs, off);
        ks += __shfl_xor(ks, off);
    }
    if (d == 0) { QQ[j] = qs; red[wv] = ks; }
    __syncthreads();
    if (threadIdx.x == 0) {
        klp[blockIdx.x] = red[0] + red[1] + red[2] + red[3];  // kl partial
        if (blockIdx.x == 0) out[0] = 0.0f;                   // zero output
    }
}

// ---------------------------------------------------------------------------
// Role B (lse), SMALL UNIT: one wave = 16-i block x 32-j chunk (NC2=64).
// s2[i][j] = QQ_j + sum_k Zx[i][k]*Wt[j][k] via 16x16x32 bf16 MFMA (2 tiles
// x 4 K-steps), row-LSE fused. 8192 units = 1 per wave of the 2048-block
// grid -> lse runs at 8 waves/SIMD (latency hidden), 4x shorter serial chain.
// C/D: col = lane&15 (j), row = (lane>>4)*4 + reg (i)  [m89-verified].
// ---------------------------------------------------------------------------
static __device__ __forceinline__ void role_lse(
    int lw, const unsigned short* __restrict__ Zx,
    const unsigned short* __restrict__ Wt, const float* __restrict__ QQ,
    float* __restrict__ wsM, float* __restrict__ wsL)
{
    int lane  = threadIdx.x & 63;
    int i0    = (lw >> 6) * 16;        // 128 i-blocks
    int chunk = lw & 63;               // 64 chunks of 32 j
    int jbase = chunk * 32;
    int r16 = lane & 15, kg = lane >> 4;

    const bf16x8* Za = (const bf16x8*)(Zx + (size_t)(i0 + r16) * 128 + kg * 8);
    bf16x8 a[4];
#pragma unroll
    for (int s = 0; s < 4; ++s) a[s] = Za[s * 4];   // stride 32 bf16 per K-step

    float m[4], l[4];
#pragma unroll
    for (int r = 0; r < 4; ++r) { m[r] = -3.0e38f; l[r] = 0.0f; }

#pragma unroll
    for (int t = 0; t < 2; ++t) {
        int j = jbase + t * 16 + r16;
        const bf16x8* Wb = (const bf16x8*)(Wt + (size_t)j * 128 + kg * 8);
        f32x4 c = (f32x4){0.0f, 0.0f, 0.0f, 0.0f};
#pragma unroll
        for (int s = 0; s < 4; ++s)
            c = __builtin_amdgcn_mfma_f32_16x16x32_bf16(a[s], Wb[s * 4], c, 0, 0, 0);
        float qq = QQ[j];
#pragma unroll
        for (int r = 0; r < 4; ++r) {
            float val = c[r] + qq;
            float delta = val - m[r];
            float e = exp2fast(-fabsf(delta));
            l[r] = (delta <= 0.0f) ? (l[r] + e) : fmaf(l[r], e, 1.0f);
            m[r] = fmaxf(m[r], val);
        }
    }
#pragma unroll
    for (int off = 8; off; off >>= 1) {
#pragma unroll
        for (int r = 0; r < 4; ++r) {
            float m2 = __shfl_xor(m[r], off);
            float l2 = __shfl_xor(l[r], off);
            float M  = fmaxf(m[r], m2);
            l[r] = fmaf(l[r], exp2fast(m[r] - M), l2 * exp2fast(m2 - M));
            m[r] = M;
        }
    }
    if (r16 == 0) {
#pragma unroll
        for (int r = 0; r < 4; ++r) {
            int i = i0 + kg * 4 + r;
            wsM[i * NC2 + chunk] = m[r];
            wsL[i * NC2 + chunk] = l[r];
        }
    }
}

// ---------------------------------------------------------------------------
// Kernel 2: TABLE BUILD + lse. F_d(z_t) = sum_j 2^(h z_t^2 + g z_t + q) on
// the G=512 z-grid (4x less work than the 2048 z samples; recovered by
// interpolation in k_fin). 2048 uniform blocks: tgroup = bid>>5 (8 t's),
// chunk = bid&31 (64-j window); wave wv sweeps 16 j for all 8 t's.
// Partials -> LDS (8KB), 4-way reduce, plain float2 stores (zero atomics).
// Then EVERY wave runs one small lse unit (lw = bid*4+wv).
// ---------------------------------------------------------------------------
__global__ __launch_bounds__(256) void k_mega(
    const uint2* __restrict__ packhg, float* __restrict__ accS,
    const unsigned short* __restrict__ Zx, const unsigned short* __restrict__ Wt,
    const float* __restrict__ QQ, float* __restrict__ wsM, float* __restrict__ wsL)
{
    __shared__ float lds[4][8 * 64];                // 8KB
    int tid  = threadIdx.x;
    int wv   = tid >> 6, lane = tid & 63;
    int bid  = blockIdx.x;
    int chunk = bid & (NCH - 1);
    int t0    = (bid >> 5) * 8;
    int j0    = chunk * 64 + wv * 16;

    v2f zt[4], zt2[4], ap[4];
#pragma unroll
    for (int kp = 0; kp < 4; ++kp) {
        float za = ZLO + (float)(t0 + 2 * kp) * DZ;
        float zb = ZLO + (float)(t0 + 2 * kp + 1) * DZ;
        zt[kp]  = (v2f){za, zb};
        zt2[kp] = (v2f){za * za, zb * zb};
        ap[kp]  = (v2f){0.0f, 0.0f};
    }

#pragma unroll 4
    for (int j = j0; j < j0 + 16; ++j) {
        uint2 p = packhg[j * D + lane];
        float h = __uint_as_float(p.x & 0xFFFF0000u);
        float g = __uint_as_float(p.x << 16);
        float q = __uint_as_float(p.y);
        v2f hh = (v2f){h, h};
        v2f gg = (v2f){g, g};
        v2f qq = (v2f){q, q};
#pragma unroll
        for (int kp = 0; kp < 4; ++kp) {
            v2f arg = zt2[kp] * hh + (zt[kp] * gg + qq);  // 2x v_pk_fma_f32
            v2f e;
            e.x = exp2fast(arg.x);
            e.y = exp2fast(arg.y);
            ap[kp] += e;                                  // v_pk_add_f32
        }
    }

#pragma unroll
    for (int kp = 0; kp < 4; ++kp) {
        lds[wv][(2 * kp) * 64 + lane]     = ap[kp].x;
        lds[wv][(2 * kp + 1) * 64 + lane] = ap[kp].y;
    }
    __syncthreads();
    {
        int e = 2 * tid;
        float s0 = lds[0][e]     + lds[1][e]     + lds[2][e]     + lds[3][e];
        float s1 = lds[0][e + 1] + lds[1][e + 1] + lds[2][e + 1] + lds[3][e + 1];
        float2* dst = (float2*)(accS + (size_t)chunk * G * D + (size_t)t0 * D);
        dst[tid] = make_float2(s0, s1);
    }

    role_lse(bid * 4 + wv, Zx, Wt, QQ, wsM, wsL);   // 8192 units, 1 per wave
}

// ---------------------------------------------------------------------------
// Kernel 2b: reduce the 32 chunk slices and take log2 -> T[t*64+d].
// ---------------------------------------------------------------------------
__global__ __launch_bounds__(256) void k_tab(
    const float* __restrict__ accS, float* __restrict__ T)
{
    int e = blockIdx.x * 256 + threadIdx.x;    // 0 .. G*D-1
    float s = 0.0f;
#pragma unroll
    for (int c = 0; c < NCH; ++c)
        s += accS[(size_t)c * G * D + e];
    T[e] = log2fast(s);
}

// ---------------------------------------------------------------------------
// Kernel 3: per-i finalization, one wave per i. lane owns d: Catmull-Rom
// interpolation of T at z[i][d] -> log2 F_d(z_id); butterfly-sum -> lqp2.
// Then the 64-chunk (M,L) merge (lane owns chunk), kl fold, 1 atomic/block.
// ---------------------------------------------------------------------------
__global__ __launch_bounds__(256) void k_fin(
    const float* __restrict__ z, const float* __restrict__ T,
    const float* __restrict__ wsM, const float* __restrict__ wsL,
    const float* __restrict__ klp, float* __restrict__ out)
{
    const float LN2 = 0.6931471805599453f;
    __shared__ float red[4];
    int lane = threadIdx.x & 63;
    int wv   = threadIdx.x >> 6;
    int i    = blockIdx.x * 4 + wv;

    float zv = z[i * D + lane];
    float tf = (zv - ZLO) * INVDZ;
    int   it = (int)floorf(tf);
    it = min(max(it, 1), G - 3);
    float u = tf - (float)it;
    float y0 = T[(it - 1) * D + lane];
    float y1 = T[it * D + lane];
    float y2 = T[(it + 1) * D + lane];
    float y3 = T[(it + 2) * D + lane];
    float ca = fmaf(1.5f, y1 - y2, 0.5f * (y3 - y0));
    float cb = y0 - 2.5f * y1 + 2.0f * y2 - 0.5f * y3;
    float cc = 0.5f * (y2 - y0);
    float lqp2 = fmaf(fmaf(fmaf(ca, u, cb), u, cc), u, y1);
#pragma unroll
    for (int off = 32; off; off >>= 1) lqp2 += __shfl_xor(lqp2, off);

    float m = wsM[i * NC2 + lane];   // lane owns chunk (NC2 == 64)
    float l = wsL[i * NC2 + lane];
#pragma unroll
    for (int off = 32; off; off >>= 1) {
        float m2 = __shfl_xor(m, off);
        float l2 = __shfl_xor(l, off);
        float M  = fmaxf(m, m2);
        l = fmaf(l, exp2fast(m - M), l2 * exp2fast(m2 - M));
        m = M;
    }

    if (lane == 0)
        red[wv] = (m + log2fast(l) - lqp2) * LN2;
    __syncthreads();
    if (threadIdx.x == 0)
        atomicAdd(out, (red[0] + red[1] + red[2] + red[3]) * (5.0f / 2048.0f)
                       + klp[blockIdx.x]);
}

// ---------------------------------------------------------------------------
extern "C" void kernel_launch(void* const* d_in, const int* in_sizes, int n_in,
                              void* d_out, int out_size, void* d_ws, size_t ws_size,
                              hipStream_t stream)
{
    const float* kl  = (const float*)d_in[0];
    const float* zm  = (const float*)d_in[1];
    const float* zlv = (const float*)d_in[2];
    const float* zs  = (const float*)d_in[3];
    float* out = (float*)d_out;
    float* ws  = (float*)d_ws;

    // workspace layout (float offsets) — total ~6.2MB
    uint2*          packhg = (uint2*)ws;                         // 2*B*D floats
    unsigned short* Zx   = (unsigned short*)(ws + 2 * B * D);    // B*D floats
    unsigned short* Wt   = (unsigned short*)(ws + 3 * B * D);    // B*D floats
    float*          QQ   = ws + 4 * B * D;                       // B
    float*          wsM  = QQ + B;                               // B*NC2
    float*          wsL  = wsM + (size_t)B * NC2;                // B*NC2
    float*          accS = wsL + (size_t)B * NC2;                // NCH*G*D
    float*          T    = accS + (size_t)NCH * G * D;           // G*D
    float*          klp  = T + (size_t)G * D;                    // 512

    k_pre<<<B / 4, 256, 0, stream>>>(kl, zm, zlv, zs, packhg, Zx, Wt, QQ, klp, out);
    k_mega<<<NBLK, 256, 0, stream>>>(packhg, accS, Zx, Wt, QQ, wsM, wsL);
    k_tab<<<(G * D) / 256, 256, 0, stream>>>(accS, T);
    k_fin<<<B / 4, 256, 0, stream>>>(zs, T, wsM, wsL, klp, out);
}

// Round 19
// 45.606 us; speedup vs baseline: 1.0066x; 1.0066x over previous
//
#include <hip/hip_runtime.h>
#include <math.h>

#define B 2048
#define D 64
#define G 512           // z-grid points for the F_d(z) table
#define NCH 32          // j-chunks for the table build
#define NC2 16          // j-chunks for the MFMA/LSE role (128 j each)
#define NBLK 2048       // (G/8) tgroups x 32 chunks

#define ZLO (-5.5f)
#define DZ  (11.0f / 511.0f)
#define INVDZ (511.0f / 11.0f)

typedef float v2f  __attribute__((ext_vector_type(2)));
typedef short bf16x8 __attribute__((ext_vector_type(8)));
typedef float f32x4  __attribute__((ext_vector_type(4)));

static __device__ __forceinline__ float exp2fast(float x) { return __builtin_amdgcn_exp2f(x); }
static __device__ __forceinline__ float log2fast(float x) { return __builtin_amdgcn_logf(x); }
static __device__ __forceinline__ unsigned short f2bf(float x) {
    unsigned u = __float_as_uint(x);
    u += 0x7fff + ((u >> 16) & 1);          // RNE; inputs are finite
    return (unsigned short)(u >> 16);
}

// ---------------------------------------------------------------------------
// Kernel 1: per-(j,d) constants (log2 units):  lp2 = h*z^2 + g*z + q
//   h = -0.5*log2e*exp(-lv), g = -2*mu*h, q = mu^2*h + c
// packhg[j*D+d] = { bf16(h)<<16 | bf16(g), fp32 q }  (8B)
// Zx/Wt = bf16 MFMA operands; QQ[j]=sum_d q; kl partials -> klp; out zeroed.
// ---------------------------------------------------------------------------
__global__ __launch_bounds__(256) void k_pre(
    const float* __restrict__ kl, const float* __restrict__ zm,
    const float* __restrict__ zlv, const float* __restrict__ zs,
    uint2* __restrict__ packhg, unsigned short* __restrict__ Zx,
    unsigned short* __restrict__ Wt, float* __restrict__ QQ,
    float* __restrict__ klp, float* __restrict__ out)
{
    const float LOG2E   = 1.4426950408889634f;
    const float LOG_2PI = 1.8378770664093453f;
    __shared__ float red[4];
    int wv = threadIdx.x >> 6, d = threadIdx.x & 63;
    int j = blockIdx.x * 4 + wv;
    int idx = j * D + d;
    float lv = zlv[idx];
    float mu = zm[idx];
    float zz = zs[idx];
    float is = exp2fast(-LOG2E * lv);            // e^{-lv}
    float h  = -0.5f * LOG2E * is;
    float cv = -0.5f * LOG2E * (lv + LOG_2PI);
    float g  = -2.0f * mu * h;
    float q  = fmaf(mu * mu, h, cv);
    packhg[idx] = make_uint2(((unsigned)f2bf(h) << 16) | f2bf(g),
                             __float_as_uint(q));
    Wt[j * 128 + d]      = f2bf(h);
    Wt[j * 128 + 64 + d] = f2bf(g);
    Zx[j * 128 + d]      = f2bf(zz * zz);
    Zx[j * 128 + 64 + d] = f2bf(zz);

    float qs = q, ks = kl[idx];
#pragma unroll
    for (int off = 32; off; off >>= 1) {
        qs += __shfl_xor(qs, off);
        ks += __shfl_xor(ks, off);
    }
    if (d == 0) { QQ[j] = qs; red[wv] = ks; }
    __syncthreads();
    if (threadIdx.x == 0) {
        klp[blockIdx.x] = red[0] + red[1] + red[2] + red[3];  // kl partial
        if (blockIdx.x == 0) out[0] = 0.0f;                   // zero output
    }
}

// ---------------------------------------------------------------------------
// Role B (lse), WAVE-PARALLEL unit: one BLOCK = 16-i x 128-j unit (NC2=16,
// 2048 units = 1 per block). The unit's 8 j-tiles are split 2-per-wave
// (serial chain cut 4x, all 4 waves busy); per-wave 16-lane butterfly, then
// a 512B LDS exchange + 16-thread cross-wave merge -> wsM/wsL.
// C/D: col = lane&15 (j), row = (lane>>4)*4 + reg (i)  [m89-verified].
// ---------------------------------------------------------------------------
static __device__ __forceinline__ void role_lse_block(
    int lw, int wv, const unsigned short* __restrict__ Zx,
    const unsigned short* __restrict__ Wt, const float* __restrict__ QQ,
    float* __restrict__ wsM, float* __restrict__ wsL,
    float* __restrict__ ldsm /* 4*16*2 floats */)
{
    int lane  = threadIdx.x & 63;
    int i0    = (lw >> 4) * 16;        // 128 i-blocks
    int chunk = lw & 15;               // 16 chunks of 128 j
    int jbase = chunk * 128;
    int r16 = lane & 15, kg = lane >> 4;

    const bf16x8* Za = (const bf16x8*)(Zx + (size_t)(i0 + r16) * 128 + kg * 8);
    bf16x8 a[4];
#pragma unroll
    for (int s = 0; s < 4; ++s) a[s] = Za[s * 4];   // stride 32 bf16 per K-step

    float m[4], l[4];
#pragma unroll
    for (int r = 0; r < 4; ++r) { m[r] = -3.0e38f; l[r] = 0.0f; }

#pragma unroll
    for (int tt = 0; tt < 2; ++tt) {
        int j = jbase + (wv * 2 + tt) * 16 + r16;
        const bf16x8* Wb = (const bf16x8*)(Wt + (size_t)j * 128 + kg * 8);
        f32x4 c = (f32x4){0.0f, 0.0f, 0.0f, 0.0f};
#pragma unroll
        for (int s = 0; s < 4; ++s)
            c = __builtin_amdgcn_mfma_f32_16x16x32_bf16(a[s], Wb[s * 4], c, 0, 0, 0);
        float qq = QQ[j];
#pragma unroll
        for (int r = 0; r < 4; ++r) {
            float val = c[r] + qq;
            float delta = val - m[r];
            float e = exp2fast(-fabsf(delta));
            l[r] = (delta <= 0.0f) ? (l[r] + e) : fmaf(l[r], e, 1.0f);
            m[r] = fmaxf(m[r], val);
        }
    }
#pragma unroll
    for (int off = 8; off; off >>= 1) {
#pragma unroll
        for (int r = 0; r < 4; ++r) {
            float m2 = __shfl_xor(m[r], off);
            float l2 = __shfl_xor(l[r], off);
            float M  = fmaxf(m[r], m2);
            l[r] = fmaf(l[r], exp2fast(m[r] - M), l2 * exp2fast(m2 - M));
            m[r] = M;
        }
    }
    if (r16 == 0) {
#pragma unroll
        for (int r = 0; r < 4; ++r) {
            int il = kg * 4 + r;                       // i-local 0..15
            ldsm[(wv * 16 + il) * 2 + 0] = m[r];
            ldsm[(wv * 16 + il) * 2 + 1] = l[r];
        }
    }
    __syncthreads();
    if (threadIdx.x < 16) {
        int il = threadIdx.x;
        float M = -3.0e38f, L = 0.0f;
#pragma unroll
        for (int w = 0; w < 4; ++w) {
            float mc = ldsm[(w * 16 + il) * 2 + 0];
            float lc = ldsm[(w * 16 + il) * 2 + 1];
            float Mn = fmaxf(M, mc);
            L = fmaf(L, exp2fast(M - Mn), lc * exp2fast(mc - Mn));
            M = Mn;
        }
        wsM[(i0 + il) * NC2 + chunk] = M;
        wsL[(i0 + il) * NC2 + chunk] = L;
    }
}

// ---------------------------------------------------------------------------
// Kernel 2: TABLE BUILD + lse. F_d(z_t) = sum_j 2^(h z_t^2 + g z_t + q) on
// the G=512 z-grid (4x less work than the 2048 z samples; recovered by
// interpolation in k_fin). 2048 uniform blocks: tgroup = bid>>5 (8 t's),
// chunk = bid&31 (64-j window); wave wv sweeps 16 j for all 8 t's.
// Partials -> LDS (8KB), 4-way reduce, plain float2 stores (zero atomics).
// Then the whole BLOCK runs one wave-parallel lse unit (lw = bid).
// ---------------------------------------------------------------------------
__global__ __launch_bounds__(256) void k_mega(
    const uint2* __restrict__ packhg, float* __restrict__ accS,
    const unsigned short* __restrict__ Zx, const unsigned short* __restrict__ Wt,
    const float* __restrict__ QQ, float* __restrict__ wsM, float* __restrict__ wsL)
{
    __shared__ float lds[4][8 * 64];                // 8KB
    __shared__ float ldsm[4 * 16 * 2];              // 512B for lse merge
    int tid  = threadIdx.x;
    int wv   = tid >> 6, lane = tid & 63;
    int bid  = blockIdx.x;
    int chunk = bid & (NCH - 1);
    int t0    = (bid >> 5) * 8;
    int j0    = chunk * 64 + wv * 16;

    v2f zt[4], zt2[4], ap[4];
#pragma unroll
    for (int kp = 0; kp < 4; ++kp) {
        float za = ZLO + (float)(t0 + 2 * kp) * DZ;
        float zb = ZLO + (float)(t0 + 2 * kp + 1) * DZ;
        zt[kp]  = (v2f){za, zb};
        zt2[kp] = (v2f){za * za, zb * zb};
        ap[kp]  = (v2f){0.0f, 0.0f};
    }

#pragma unroll 4
    for (int j = j0; j < j0 + 16; ++j) {
        uint2 p = packhg[j * D + lane];
        float h = __uint_as_float(p.x & 0xFFFF0000u);
        float g = __uint_as_float(p.x << 16);
        float q = __uint_as_float(p.y);
        v2f hh = (v2f){h, h};
        v2f gg = (v2f){g, g};
        v2f qq = (v2f){q, q};
#pragma unroll
        for (int kp = 0; kp < 4; ++kp) {
            v2f arg = zt2[kp] * hh + (zt[kp] * gg + qq);  // 2x v_pk_fma_f32
            v2f e;
            e.x = exp2fast(arg.x);
            e.y = exp2fast(arg.y);
            ap[kp] += e;                                  // v_pk_add_f32
        }
    }

#pragma unroll
    for (int kp = 0; kp < 4; ++kp) {
        lds[wv][(2 * kp) * 64 + lane]     = ap[kp].x;
        lds[wv][(2 * kp + 1) * 64 + lane] = ap[kp].y;
    }
    __syncthreads();
    {
        int e = 2 * tid;
        float s0 = lds[0][e]     + lds[1][e]     + lds[2][e]     + lds[3][e];
        float s1 = lds[0][e + 1] + lds[1][e + 1] + lds[2][e + 1] + lds[3][e + 1];
        float2* dst = (float2*)(accS + (size_t)chunk * G * D + (size_t)t0 * D);
        dst[tid] = make_float2(s0, s1);
    }

    role_lse_block(bid, wv, Zx, Wt, QQ, wsM, wsL, ldsm);  // 2048 units
}

// ---------------------------------------------------------------------------
// Kernel 2b: reduce the 32 chunk slices and take log2 -> T[t*64+d].
// ---------------------------------------------------------------------------
__global__ __launch_bounds__(256) void k_tab(
    const float* __restrict__ accS, float* __restrict__ T)
{
    int e = blockIdx.x * 256 + threadIdx.x;    // 0 .. G*D-1
    float s = 0.0f;
#pragma unroll
    for (int c = 0; c < NCH; ++c)
        s += accS[(size_t)c * G * D + e];
    T[e] = log2fast(s);
}

// ---------------------------------------------------------------------------
// Kernel 3: per-i finalization, one wave per i. lane owns d: Catmull-Rom
// interpolation of T at z[i][d] -> log2 F_d(z_id); butterfly-sum -> lqp2.
// Then the 16-chunk (M,L) merge, kl fold, one atomic per block.
// ---------------------------------------------------------------------------
__global__ __launch_bounds__(256) void k_fin(
    const float* __restrict__ z, const float* __restrict__ T,
    const float* __restrict__ wsM, const float* __restrict__ wsL,
    const float* __restrict__ klp, float* __restrict__ out)
{
    const float LN2 = 0.6931471805599453f;
    __shared__ float red[4];
    int lane = threadIdx.x & 63;
    int wv   = threadIdx.x >> 6;
    int i    = blockIdx.x * 4 + wv;

    float zv = z[i * D + lane];
    float tf = (zv - ZLO) * INVDZ;
    int   it = (int)floorf(tf);
    it = min(max(it, 1), G - 3);
    float u = tf - (float)it;
    float y0 = T[(it - 1) * D + lane];
    float y1 = T[it * D + lane];
    float y2 = T[(it + 1) * D + lane];
    float y3 = T[(it + 2) * D + lane];
    float ca = fmaf(1.5f, y1 - y2, 0.5f * (y3 - y0));
    float cb = y0 - 2.5f * y1 + 2.0f * y2 - 0.5f * y3;
    float cc = 0.5f * (y2 - y0);
    float lqp2 = fmaf(fmaf(fmaf(ca, u, cb), u, cc), u, y1);
#pragma unroll
    for (int off = 32; off; off >>= 1) lqp2 += __shfl_xor(lqp2, off);

    float m = -3.0e38f, l = 0.0f;
    if (lane < NC2) { m = wsM[i * NC2 + lane]; l = wsL[i * NC2 + lane]; }
#pragma unroll
    for (int off = 32; off; off >>= 1) {
        float m2 = __shfl_xor(m, off);
        float l2 = __shfl_xor(l, off);
        float M  = fmaxf(m, m2);
        l = fmaf(l, exp2fast(m - M), l2 * exp2fast(m2 - M));
        m = M;
    }

    if (lane == 0)
        red[wv] = (m + log2fast(l) - lqp2) * LN2;
    __syncthreads();
    if (threadIdx.x == 0)
        atomicAdd(out, (red[0] + red[1] + red[2] + red[3]) * (5.0f / 2048.0f)
                       + klp[blockIdx.x]);
}

// ---------------------------------------------------------------------------
extern "C" void kernel_launch(void* const* d_in, const int* in_sizes, int n_in,
                              void* d_out, int out_size, void* d_ws, size_t ws_size,
                              hipStream_t stream)
{
    const float* kl  = (const float*)d_in[0];
    const float* zm  = (const float*)d_in[1];
    const float* zlv = (const float*)d_in[2];
    const float* zs  = (const float*)d_in[3];
    float* out = (float*)d_out;
    float* ws  = (float*)d_ws;

    // workspace layout (float offsets) — total ~6.2MB
    uint2*          packhg = (uint2*)ws;                         // 2*B*D floats
    unsigned short* Zx   = (unsigned short*)(ws + 2 * B * D);    // B*D floats
    unsigned short* Wt   = (unsigned short*)(ws + 3 * B * D);    // B*D floats
    float*          QQ   = ws + 4 * B * D;                       // B
    float*          wsM  = QQ + B;                               // B*NC2
    float*          wsL  = wsM + (size_t)B * NC2;                // B*NC2
    float*          accS = wsL + (size_t)B * NC2;                // NCH*G*D
    float*          T    = accS + (size_t)NCH * G * D;           // G*D
    float*          klp  = T + (size_t)G * D;                    // 512

    k_pre<<<B / 4, 256, 0, stream>>>(kl, zm, zlv, zs, packhg, Zx, Wt, QQ, klp, out);
    k_mega<<<NBLK, 256, 0, stream>>>(packhg, accS, Zx, Wt, QQ, wsM, wsL);
    k_tab<<<(G * D) / 256, 256, 0, stream>>>(accS, T);
    k_fin<<<B / 4, 256, 0, stream>>>(zs, T, wsM, wsL, klp, out);
}